// Round 3
// baseline (83.450 us; speedup 1.0000x reference)
//
#include <hip/hip_runtime.h>

#define HH 64
#define WW 64
#define PIN 64
#define POUT 64
#define NFEAT 54

typedef _Float16 half8 __attribute__((ext_vector_type(8)));
typedef _Float16 half4 __attribute__((ext_vector_type(4)));
typedef float f32x4 __attribute__((ext_vector_type(4)));

// ---------------- filter prep ----------------
// Fprep[f][o][c] fp16, f enumerates (k,l): k=0,l=1..9 (linear, coef F[0,l]+F[l,0]);
// k=1..9, l=k..9 (quad, coef F[k,l]+F[l,k], diag F[k,k]). Fconst[o] = bias + sum_c F[o,c,0,0].
__global__ void prep_filters(const float* __restrict__ f, const float* __restrict__ bias,
                             _Float16* __restrict__ fprep, float* __restrict__ fconst) {
    int blk = blockIdx.x;
    if (blk == NFEAT) {
        int o = threadIdx.x;
        if (o < POUT) {
            float s = bias[o];
            for (int c = 0; c < PIN; ++c) s += f[(size_t)(o * PIN + c) * 100];
            fconst[o] = s;
        }
        return;
    }
    // decode feature id -> (k,l)
    int k = 0, l = 0, cnt = 0;
    for (int kk = 0; kk <= 9; ++kk) {
        int ls = (kk == 0) ? 1 : kk;
        for (int ll = ls; ll <= 9; ++ll) {
            if (cnt == blk) { k = kk; l = ll; }
            ++cnt;
        }
    }
    for (int i = threadIdx.x; i < POUT * PIN; i += blockDim.x) {
        int o = i >> 6, c = i & 63;
        const float* fc = f + (size_t)(o * PIN + c) * 100;
        float v;
        if (k == 0)      v = fc[l] + fc[l * 10];
        else if (k == l) v = fc[k * 10 + k];
        else             v = fc[k * 10 + l] + fc[l * 10 + k];
        fprep[((size_t)blk * POUT + o) * PIN + c] = (_Float16)v;
    }
}

// ---------------- main MFMA kernel ----------------
// block = 2 output rows x 64 w = 256 pixels, 4 waves: wave w covers row (w>>1), w-half (w&1)*32.
// Wave tile: 32 m x 64 n, 16x16x32 f16 MFMA, K = 64 channels split in 2 kc halves.
__global__ __launch_bounds__(256) void poly2d_mfma(
    const float* __restrict__ x, const _Float16* __restrict__ fprep,
    const float* __restrict__ fconst, float* __restrict__ out)
{
    __shared__ __align__(16) char smem[33792]; // x tile [4][66][8cg swz][8 f16]; reused as out stage [128][65] f32

    const int t = threadIdx.x;
    const int bid = blockIdx.x;
    const int b = bid >> 5;
    const int h0 = (bid & 31) * 2;

    // ---- stage x tile (rows h0-1..h0+2, w -1..64, all 64 c) as swizzled fp16 ----
    {
        const int w = t & 63;
        const int cq = (t >> 6) * 4;
        for (int h = 0; h < 4; ++h) {
            int h_in = h0 - 1 + h;
            bool hok = ((unsigned)h_in < HH);
            #pragma unroll
            for (int cc = 0; cc < 4; ++cc) {
                int c = cq + cc * 16;
                float v0 = 0.f, v1 = 0.f, v2 = 0.f, v3 = 0.f;
                if (hok) {
                    const float* gx = x + (((size_t)b * PIN + c) * HH + h_in) * WW + w;
                    v0 = gx[0]; v1 = gx[4096]; v2 = gx[2 * 4096]; v3 = gx[3 * 4096];
                }
                half4 pk = {(_Float16)v0, (_Float16)v1, (_Float16)v2, (_Float16)v3};
                int wl = w + 1;
                int byte = ((h * 66 + wl) * 8 + ((c >> 3) ^ (wl & 7))) * 16 + (c & 7) * 2;
                *(half4*)(smem + byte) = pk;
            }
        }
        if (t < 64) { // w halo (input w=-1 and w=64 are always out of image -> zero)
            int h = t & 3, side = (t >> 2) & 1, cg = t >> 3;
            int wl = side ? 65 : 0;
            int byte = ((h * 66 + wl) * 8 + (cg ^ (wl & 7))) * 16;
            f32x4 z = {0.f, 0.f, 0.f, 0.f};
            *(f32x4*)(smem + byte) = z;
        }
    }
    __syncthreads();

    const int wid = t >> 6;
    const int lane = t & 63;
    const int hh = wid >> 1;           // output row within block (0/1)
    const int wbase = (wid & 1) * 32;  // w half
    const int ln15 = lane & 15;
    const int lq = lane >> 4;          // 0..3

    f32x4 acc[2][4] = {};

    #pragma unroll
    for (int kc = 0; kc < 2; ++kc) {
        // load 9 shift panels + ones into registers (frag: m=ln15, k=lq*8+j)
        half8 xp[10][2];
        #pragma unroll
        for (int mb = 0; mb < 2; ++mb) {
            half8 ones = {(_Float16)1.f, (_Float16)1.f, (_Float16)1.f, (_Float16)1.f,
                          (_Float16)1.f, (_Float16)1.f, (_Float16)1.f, (_Float16)1.f};
            xp[0][mb] = ones;
        }
        #pragma unroll
        for (int p = 1; p <= 9; ++p) {
            const int dh = (p - 1) / 3 - 1, dw = (p - 1) % 3 - 1;
            #pragma unroll
            for (int mb = 0; mb < 2; ++mb) {
                int wpix = wbase + mb * 16 + ln15;
                int wl = wpix + dw + 1;
                int hidx = hh + dh + 1;
                int cg = kc * 4 + lq;
                int byte = ((hidx * 66 + wl) * 8 + (cg ^ (wl & 7))) * 16;
                xp[p][mb] = *(const half8*)(smem + byte);
            }
        }
        // B-frag ring prefetch (depth 2) straight from global (L2-resident Fprep)
        half8 Bbuf[3][4];
        const _Float16* fb = fprep + ln15 * 64 + lq * 8 + kc * 32;
        #pragma unroll
        for (int nb = 0; nb < 4; ++nb) Bbuf[0][nb] = *(const half8*)(fb + nb * 1024);
        #pragma unroll
        for (int nb = 0; nb < 4; ++nb) Bbuf[1][nb] = *(const half8*)(fb + 4096 + nb * 1024);

        int fidx = 0;
        #pragma unroll
        for (int k = 0; k <= 9; ++k) {
            #pragma unroll
            for (int l = (k == 0 ? 1 : k); l <= 9; ++l) {
                const int f = fidx;
                if (f + 2 < NFEAT) {
                    #pragma unroll
                    for (int nb = 0; nb < 4; ++nb)
                        Bbuf[(f + 2) % 3][nb] =
                            *(const half8*)(fb + (size_t)(f + 2) * 4096 + nb * 1024);
                }
                half8 prod0 = xp[k][0] * xp[l][0];
                half8 prod1 = xp[k][1] * xp[l][1];
                #pragma unroll
                for (int nb = 0; nb < 4; ++nb) {
                    acc[0][nb] = __builtin_amdgcn_mfma_f32_16x16x32_f16(
                        prod0, Bbuf[f % 3][nb], acc[0][nb], 0, 0, 0);
                    acc[1][nb] = __builtin_amdgcn_mfma_f32_16x16x32_f16(
                        prod1, Bbuf[f % 3][nb], acc[1][nb], 0, 0, 0);
                }
                ++fidx;
            }
        }
    }

    __syncthreads(); // everyone done reading x tile; reuse smem for output transpose
    float* os = (float*)smem; // [128 m][65]
    #pragma unroll
    for (int mb = 0; mb < 2; ++mb)
        #pragma unroll
        for (int nb = 0; nb < 4; ++nb)
            #pragma unroll
            for (int j = 0; j < 4; ++j) {
                int m = wid * 32 + mb * 16 + lq * 4 + j; // C/D: row=(lane>>4)*4+reg
                int o = nb * 16 + ln15;                  //      col=lane&15
                os[m * 65 + o] = acc[mb][nb][j];
            }
    __syncthreads();

    { // coalesced store: lanes sweep w
        const int w = t & 63;
        const int og = t >> 6;
        #pragma unroll
        for (int h2 = 0; h2 < 2; ++h2) {
            #pragma unroll
            for (int oo = 0; oo < 16; ++oo) {
                int o = og * 16 + oo;
                int m = (h2 * 2 + (w >> 5)) * 32 + (w & 31);
                float val = os[m * 65 + o] + fconst[o];
                out[(((size_t)b * POUT + o) * HH + (h0 + h2)) * WW + w] = val;
            }
        }
    }
}

// ---------------- fp32 fallback (round-1 kernel), used only if ws too small ----------------
__global__ __launch_bounds__(256) void poly2d_fp32(
    const float* __restrict__ x, const float* __restrict__ f,
    const float* __restrict__ bias, float* __restrict__ out)
{
    const int t = threadIdx.x;
    const int wo = t & 63;
    const int ho = (blockIdx.x & 15) * 4 + (t >> 6);
    const int o = (blockIdx.x >> 4) & 63;
    const int b = blockIdx.x >> 10;

    float acc = bias[o];
    const float* xb = x + (size_t)b * PIN * HH * WW;
    const float* fo = f + (size_t)o * PIN * 100;
    for (int c = 0; c < PIN; ++c) {
        const float* xc = xb + (size_t)c * HH * WW;
        float s[10];
        s[0] = 1.0f;
        #pragma unroll
        for (int kh = 0; kh < 3; ++kh) {
            int h = ho - 1 + kh;
            bool hok = ((unsigned)h < HH);
            #pragma unroll
            for (int kw = 0; kw < 3; ++kw) {
                int w = wo - 1 + kw;
                s[1 + kh * 3 + kw] = (hok && (unsigned)w < WW) ? xc[h * WW + w] : 0.0f;
            }
        }
        const float* fc = fo + c * 100;
        #pragma unroll
        for (int i = 0; i < 10; ++i) {
            float wsum = 0.0f;
            #pragma unroll
            for (int j = 0; j < 10; ++j) wsum = fmaf(fc[i * 10 + j], s[j], wsum);
            acc = fmaf(wsum, s[i], acc);
        }
    }
    out[(((size_t)b * POUT + o) * HH + ho) * WW + wo] = acc;
}

extern "C" void kernel_launch(void* const* d_in, const int* in_sizes, int n_in,
                              void* d_out, int out_size, void* d_ws, size_t ws_size,
                              hipStream_t stream) {
    const float* x    = (const float*)d_in[0];
    const float* filt = (const float*)d_in[1];
    const float* bias = (const float*)d_in[2];
    float* out = (float*)d_out;

    const size_t FPREP_BYTES = (size_t)NFEAT * POUT * PIN * 2; // 442368
    if (ws_size < FPREP_BYTES + 256) {
        poly2d_fp32<<<dim3(8 * 64 * 16), dim3(256), 0, stream>>>(x, filt, bias, out);
        return;
    }
    _Float16* fprep = (_Float16*)d_ws;
    float* fconst = (float*)((char*)d_ws + FPREP_BYTES);

    prep_filters<<<dim3(NFEAT + 1), dim3(256), 0, stream>>>(filt, bias, fprep, fconst);
    poly2d_mfma<<<dim3(256), dim3(256), 0, stream>>>(x, fprep, fconst, out);
}

// Round 4
// 82.352 us; speedup vs baseline: 1.0133x; 1.0133x over previous
//
#include <hip/hip_runtime.h>

#define HH 64
#define WW 64
#define PIN 64
#define POUT 64
#define NFEAT 54

typedef _Float16 half8 __attribute__((ext_vector_type(8)));
typedef _Float16 half4 __attribute__((ext_vector_type(4)));
typedef float f32x4 __attribute__((ext_vector_type(4)));

// ---------------- filter prep ----------------
// Fprep[f][o][c] fp16, f enumerates (k,l): k=0,l=1..9 (linear, coef F[0,l]+F[l,0]);
// k=1..9, l=k..9 (quad, coef F[k,l]+F[l,k], diag F[k,k]). Fconst[o] = bias + sum_c F[o,c,0,0].
__global__ void prep_filters(const float* __restrict__ f, const float* __restrict__ bias,
                             _Float16* __restrict__ fprep, float* __restrict__ fconst) {
    int blk = blockIdx.x;
    if (blk == NFEAT) {
        int o = threadIdx.x;
        if (o < POUT) {
            float s = bias[o];
            for (int c = 0; c < PIN; ++c) s += f[(size_t)(o * PIN + c) * 100];
            fconst[o] = s;
        }
        return;
    }
    // decode feature id -> (k,l)
    int k = 0, l = 0, cnt = 0;
    for (int kk = 0; kk <= 9; ++kk) {
        int ls = (kk == 0) ? 1 : kk;
        for (int ll = ls; ll <= 9; ++ll) {
            if (cnt == blk) { k = kk; l = ll; }
            ++cnt;
        }
    }
    for (int i = threadIdx.x; i < POUT * PIN; i += blockDim.x) {
        int o = i >> 6, c = i & 63;
        const float* fc = f + (size_t)(o * PIN + c) * 100;
        float v;
        if (k == 0)      v = fc[l] + fc[l * 10];
        else if (k == l) v = fc[k * 10 + k];
        else             v = fc[k * 10 + l] + fc[l * 10 + k];
        fprep[((size_t)blk * POUT + o) * PIN + c] = (_Float16)v;
    }
}

// ---------------- main MFMA kernel ----------------
// block = 2 output rows x 64 w = 256 pixels, 4 waves: wave w covers row (w>>1), w-half (w&1)*32.
// Wave tile: 32 m x 64 n, 16x16x32 f16 MFMA, K = 64 channels split in 2 kc halves.
__global__ __launch_bounds__(256) void poly2d_mfma(
    const float* __restrict__ x, const _Float16* __restrict__ fprep,
    const float* __restrict__ fconst, float* __restrict__ out)
{
    __shared__ __align__(16) char smem[33792]; // x tile [4][66][8cg swz][8 f16]; reused as out stage [128][65] f32

    const int t = threadIdx.x;
    const int bid = blockIdx.x;
    const int b = bid >> 5;
    const int h0 = (bid & 31) * 2;

    // ---- stage x tile (rows h0-1..h0+2, w -1..64, all 64 c) as swizzled fp16 ----
    {
        const int w = t & 63;
        const int cq = (t >> 6) * 4;
        for (int h = 0; h < 4; ++h) {
            int h_in = h0 - 1 + h;
            bool hok = ((unsigned)h_in < HH);
            #pragma unroll
            for (int cc = 0; cc < 4; ++cc) {
                int c = cq + cc * 16;
                float v0 = 0.f, v1 = 0.f, v2 = 0.f, v3 = 0.f;
                if (hok) {
                    const float* gx = x + (((size_t)b * PIN + c) * HH + h_in) * WW + w;
                    v0 = gx[0]; v1 = gx[4096]; v2 = gx[2 * 4096]; v3 = gx[3 * 4096];
                }
                half4 pk = {(_Float16)v0, (_Float16)v1, (_Float16)v2, (_Float16)v3};
                int wl = w + 1;
                int byte = ((h * 66 + wl) * 8 + ((c >> 3) ^ (wl & 7))) * 16 + (c & 7) * 2;
                *(half4*)(smem + byte) = pk;
            }
        }
        if (t < 64) { // w halo (input w=-1 and w=64 are always out of image -> zero)
            int h = t & 3, side = (t >> 2) & 1, cg = t >> 3;
            int wl = side ? 65 : 0;
            int byte = ((h * 66 + wl) * 8 + (cg ^ (wl & 7))) * 16;
            f32x4 z = {0.f, 0.f, 0.f, 0.f};
            *(f32x4*)(smem + byte) = z;
        }
    }
    __syncthreads();

    const int wid = t >> 6;
    const int lane = t & 63;
    const int hh = wid >> 1;           // output row within block (0/1)
    const int wbase = (wid & 1) * 32;  // w half
    const int ln15 = lane & 15;
    const int lq = lane >> 4;          // 0..3

    f32x4 acc[2][4] = {};

    #pragma unroll
    for (int kc = 0; kc < 2; ++kc) {
        // load 9 shift panels + ones into registers (frag: m=ln15, k=lq*8+j)
        half8 xp[10][2];
        #pragma unroll
        for (int mb = 0; mb < 2; ++mb) {
            half8 ones = {(_Float16)1.f, (_Float16)1.f, (_Float16)1.f, (_Float16)1.f,
                          (_Float16)1.f, (_Float16)1.f, (_Float16)1.f, (_Float16)1.f};
            xp[0][mb] = ones;
        }
        #pragma unroll
        for (int p = 1; p <= 9; ++p) {
            const int dh = (p - 1) / 3 - 1, dw = (p - 1) % 3 - 1;
            #pragma unroll
            for (int mb = 0; mb < 2; ++mb) {
                int wpix = wbase + mb * 16 + ln15;
                int wl = wpix + dw + 1;
                int hidx = hh + dh + 1;
                int cg = kc * 4 + lq;
                int byte = ((hidx * 66 + wl) * 8 + (cg ^ (wl & 7))) * 16;
                xp[p][mb] = *(const half8*)(smem + byte);
            }
        }
        // B-frag ring prefetch (depth 2) straight from global (L2-resident Fprep)
        half8 Bbuf[3][4];
        const _Float16* fb = fprep + ln15 * 64 + lq * 8 + kc * 32;
        #pragma unroll
        for (int nb = 0; nb < 4; ++nb) Bbuf[0][nb] = *(const half8*)(fb + nb * 1024);
        #pragma unroll
        for (int nb = 0; nb < 4; ++nb) Bbuf[1][nb] = *(const half8*)(fb + 4096 + nb * 1024);

        int fidx = 0;
        #pragma unroll
        for (int k = 0; k <= 9; ++k) {
            #pragma unroll
            for (int l = (k == 0 ? 1 : k); l <= 9; ++l) {
                const int f = fidx;
                if (f + 2 < NFEAT) {
                    #pragma unroll
                    for (int nb = 0; nb < 4; ++nb)
                        Bbuf[(f + 2) % 3][nb] =
                            *(const half8*)(fb + (size_t)(f + 2) * 4096 + nb * 1024);
                }
                half8 prod0 = xp[k][0] * xp[l][0];
                half8 prod1 = xp[k][1] * xp[l][1];
                #pragma unroll
                for (int nb = 0; nb < 4; ++nb) {
                    acc[0][nb] = __builtin_amdgcn_mfma_f32_16x16x32_f16(
                        prod0, Bbuf[f % 3][nb], acc[0][nb], 0, 0, 0);
                    acc[1][nb] = __builtin_amdgcn_mfma_f32_16x16x32_f16(
                        prod1, Bbuf[f % 3][nb], acc[1][nb], 0, 0, 0);
                }
                ++fidx;
            }
        }
    }

    __syncthreads(); // everyone done reading x tile; reuse smem for output transpose
    float* os = (float*)smem; // [128 m][65]
    #pragma unroll
    for (int mb = 0; mb < 2; ++mb)
        #pragma unroll
        for (int nb = 0; nb < 4; ++nb)
            #pragma unroll
            for (int j = 0; j < 4; ++j) {
                int m = wid * 32 + mb * 16 + lq * 4 + j; // C/D: row=(lane>>4)*4+reg
                int o = nb * 16 + ln15;                  //      col=lane&15
                os[m * 65 + o] = acc[mb][nb][j];
            }
    __syncthreads();

    { // coalesced store: lanes sweep w
        const int w = t & 63;
        const int og = t >> 6;
        #pragma unroll
        for (int h2 = 0; h2 < 2; ++h2) {
            #pragma unroll
            for (int oo = 0; oo < 16; ++oo) {
                int o = og * 16 + oo;
                int m = (h2 * 2 + (w >> 5)) * 32 + (w & 31);
                float val = os[m * 65 + o] + fconst[o];
                out[(((size_t)b * POUT + o) * HH + (h0 + h2)) * WW + w] = val;
            }
        }
    }
}

// ---------------- fp32 fallback (round-1 kernel), used only if ws too small ----------------
__global__ __launch_bounds__(256) void poly2d_fp32(
    const float* __restrict__ x, const float* __restrict__ f,
    const float* __restrict__ bias, float* __restrict__ out)
{
    const int t = threadIdx.x;
    const int wo = t & 63;
    const int ho = (blockIdx.x & 15) * 4 + (t >> 6);
    const int o = (blockIdx.x >> 4) & 63;
    const int b = blockIdx.x >> 10;

    float acc = bias[o];
    const float* xb = x + (size_t)b * PIN * HH * WW;
    const float* fo = f + (size_t)o * PIN * 100;
    for (int c = 0; c < PIN; ++c) {
        const float* xc = xb + (size_t)c * HH * WW;
        float s[10];
        s[0] = 1.0f;
        #pragma unroll
        for (int kh = 0; kh < 3; ++kh) {
            int h = ho - 1 + kh;
            bool hok = ((unsigned)h < HH);
            #pragma unroll
            for (int kw = 0; kw < 3; ++kw) {
                int w = wo - 1 + kw;
                s[1 + kh * 3 + kw] = (hok && (unsigned)w < WW) ? xc[h * WW + w] : 0.0f;
            }
        }
        const float* fc = fo + c * 100;
        #pragma unroll
        for (int i = 0; i < 10; ++i) {
            float wsum = 0.0f;
            #pragma unroll
            for (int j = 0; j < 10; ++j) wsum = fmaf(fc[i * 10 + j], s[j], wsum);
            acc = fmaf(wsum, s[i], acc);
        }
    }
    out[(((size_t)b * POUT + o) * HH + ho) * WW + wo] = acc;
}

extern "C" void kernel_launch(void* const* d_in, const int* in_sizes, int n_in,
                              void* d_out, int out_size, void* d_ws, size_t ws_size,
                              hipStream_t stream) {
    const float* x    = (const float*)d_in[0];
    const float* filt = (const float*)d_in[1];
    const float* bias = (const float*)d_in[2];
    float* out = (float*)d_out;

    const size_t FPREP_BYTES = (size_t)NFEAT * POUT * PIN * 2; // 442368
    if (ws_size < FPREP_BYTES + 256) {
        poly2d_fp32<<<dim3(8 * 64 * 16), dim3(256), 0, stream>>>(x, filt, bias, out);
        return;
    }
    _Float16* fprep = (_Float16*)d_ws;
    float* fconst = (float*)((char*)d_ws + FPREP_BYTES);

    prep_filters<<<dim3(NFEAT + 1), dim3(256), 0, stream>>>(filt, bias, fprep, fconst);
    poly2d_mfma<<<dim3(256), dim3(256), 0, stream>>>(x, fprep, fconst, out);
}